// Round 2
// baseline (4113.385 us; speedup 1.0000x reference)
//
#include <hip/hip_runtime.h>

#define NN 20000
#define NK 2
#define KD 10
#define FC 256    // combined width
#define FH 128    // hidden width
#define NE 640000

// ---------------- CSR build ----------------

__global__ __launch_bounds__(256) void k_hist(const int* __restrict__ ei, int* __restrict__ cnt) {
    int i = blockIdx.x * 256 + threadIdx.x;          // 0 .. 2*NE-1 (grid exact)
    int k = i / NE, e = i - k * NE;
    int dst = ei[(size_t)k * 2 * NE + NE + e];
    atomicAdd(&cnt[k * NN + dst], 1);
}

__global__ __launch_bounds__(1024) void k_scan(const int* __restrict__ cnt, int* __restrict__ rp) {
    int k = blockIdx.x;
    __shared__ int part[1024];
    int t = threadIdx.x;
    int loc[20];
    int s = 0;
    if (t < 1000) {
#pragma unroll
        for (int j = 0; j < 20; ++j) { loc[j] = cnt[k * NN + t * 20 + j]; s += loc[j]; }
    }
    part[t] = s;
    __syncthreads();
    for (int off = 1; off < 1024; off <<= 1) {
        int add = (t >= off) ? part[t - off] : 0;
        __syncthreads();
        part[t] += add;
        __syncthreads();
    }
    int excl = (t == 0) ? 0 : part[t - 1];
    if (t < 1000) {
        int run = excl;
#pragma unroll
        for (int j = 0; j < 20; ++j) { rp[k * (NN + 1) + t * 20 + j] = run; run += loc[j]; }
        if (t == 999) rp[k * (NN + 1) + NN] = run;
    }
}

__global__ __launch_bounds__(256) void k_fill(const int* __restrict__ ei, const float* __restrict__ ew,
                                              const int* __restrict__ rp, int* __restrict__ fcnt,
                                              int* __restrict__ esrc, float* __restrict__ ewt) {
    int i = blockIdx.x * 256 + threadIdx.x;
    int k = i / NE, e = i - k * NE;
    int src = ei[(size_t)k * 2 * NE + e];
    int dst = ei[(size_t)k * 2 * NE + NE + e];
    int pos = rp[k * (NN + 1) + dst] + atomicAdd(&fcnt[k * NN + dst], 1);
    esrc[(size_t)k * NE + pos] = src;
    ewt[(size_t)k * NE + pos]  = ew[(size_t)k * NE + e];
}

// ---------------- combined build ----------------

__global__ __launch_bounds__(256) void k_comb(const float* __restrict__ in, const float* __restrict__ hid,
                                              float* __restrict__ comb) {
    int i = blockIdx.x * 256 + threadIdx.x;          // 0 .. NN*64-1 (float4 per slot)
    int r = i >> 6, c4 = i & 63;
    const float4* srcp = (c4 < 32) ? (const float4*)(in + (size_t)r * FH)
                                   : (const float4*)(hid + (size_t)r * FH);
    int cc = (c4 < 32) ? c4 : (c4 - 32);
    ((float4*)(comb + (size_t)r * FC))[c4] = srcp[cc];
}

// ---------------- y = x @ W_blk  (N x 256) @ (256 x 128) ----------------
// BM=32, 256 threads, micro-tile 4x4 per thread.

__global__ __launch_bounds__(256) void k_gemm(const float* __restrict__ x, const float* __restrict__ W,
                                              float* __restrict__ y, int blk) {
    __shared__ float xst[32][36];    // [kk][row], transposed x tile, padded
    __shared__ float wsm[32][132];   // [kk][col], padded
    int t = threadIdx.x;
    int bm = blockIdx.x * 32;
    int ty = t >> 5, tx = t & 31;
    float acc[4][4] = {};
    const float* Wb = W + (size_t)blk * 256 * 128;
    for (int k0 = 0; k0 < 256; k0 += 32) {
        {
            int r = t >> 3, c4 = (t & 7) << 2;
            float4 v = *(const float4*)(x + (size_t)(bm + r) * FC + k0 + c4);
            xst[c4 + 0][r] = v.x; xst[c4 + 1][r] = v.y; xst[c4 + 2][r] = v.z; xst[c4 + 3][r] = v.w;
#pragma unroll
            for (int j = 0; j < 4; ++j) {
                int idx = t + j * 256;
                int rr = idx >> 5, cc4 = (idx & 31) << 2;
                *(float4*)&wsm[rr][cc4] = *(const float4*)(Wb + (size_t)(k0 + rr) * 128 + cc4);
            }
        }
        __syncthreads();
#pragma unroll
        for (int kk = 0; kk < 32; ++kk) {
            float4 a4 = *(const float4*)&xst[kk][ty << 2];
            float4 w4 = *(const float4*)&wsm[kk][tx << 2];
            float a[4] = {a4.x, a4.y, a4.z, a4.w};
            float wv[4] = {w4.x, w4.y, w4.z, w4.w};
#pragma unroll
            for (int i2 = 0; i2 < 4; ++i2)
#pragma unroll
                for (int j2 = 0; j2 < 4; ++j2) acc[i2][j2] += a[i2] * wv[j2];
        }
        __syncthreads();
    }
#pragma unroll
    for (int i2 = 0; i2 < 4; ++i2) {
        int gr = bm + (ty << 2) + i2;
        *(float4*)(y + (size_t)gr * FH + (tx << 2)) = *(float4*)&acc[i2][0];
    }
}

// ---------------- Clenshaw SPMM step ----------------
// mode 0: out = y + 2*(A b1)            (b2 unused)
// mode 1: out = y + 2*(A b1) - b2
// mode 2: out += (A b1) - b2            (y unused; accumulate into out)

__global__ __launch_bounds__(256) void k_spmm(const int* __restrict__ rp, const int* __restrict__ esrc,
                                              const float* __restrict__ ewt,
                                              const float* __restrict__ b1, const float* __restrict__ b2,
                                              const float* __restrict__ y, float* __restrict__ out, int mode) {
    int gid = blockIdx.x * 256 + threadIdx.x;
    int row = gid >> 6;          // one wave64 per dst row
    int lane = gid & 63;
    int beg = rp[row], end = rp[row + 1];
    const float2* b1v = (const float2*)b1;
    float ax = 0.f, ay = 0.f;
    for (int e = beg; e < end; ++e) {
        int s = esrc[e];
        float w = ewt[e];
        float2 v = b1v[(size_t)s * 64 + lane];
        ax += w * v.x; ay += w * v.y;
    }
    size_t o = (size_t)row * 64 + lane;
    float2 res;
    if (mode == 0) {
        float2 yv = ((const float2*)y)[o];
        res.x = yv.x + 2.f * ax; res.y = yv.y + 2.f * ay;
    } else if (mode == 1) {
        float2 yv = ((const float2*)y)[o];
        float2 bv = ((const float2*)b2)[o];
        res.x = yv.x + 2.f * ax - bv.x; res.y = yv.y + 2.f * ay - bv.y;
    } else {
        float2 ov = ((float2*)out)[o];
        float2 bv = ((const float2*)b2)[o];
        res.x = ov.x + ax - bv.x; res.y = ov.y + ay - bv.y;
    }
    ((float2*)out)[o] = res;
}

// ---------------- activations ----------------

__global__ __launch_bounds__(256) void k_act(const float* __restrict__ S, const float* __restrict__ bvec,
                                             const float* __restrict__ hid, float* __restrict__ rbuf,
                                             float* __restrict__ comb) {
    int i = blockIdx.x * 256 + threadIdx.x;          // NN*128
    int r = i >> 7, c = i & 127;
    float v = 1.f / (1.f + expf(-(S[i] + bvec[c])));
    rbuf[i] = v;
    comb[(size_t)r * FC + 128 + c] = v * hid[i];     // input half of comb is already there
}

__global__ __launch_bounds__(256) void k_final(const float* __restrict__ S, const float* __restrict__ bvec,
                                               const float* __restrict__ hid, const float* __restrict__ rbuf,
                                               float* __restrict__ out) {
    int i = blockIdx.x * 256 + threadIdx.x;
    int c = i & 127;
    float C = 1.f / (1.f + expf(-(S[i] + bvec[c])));
    float u = rbuf[i];
    out[i] = u * hid[i] + (1.f - u) * C;
}

// ---------------- launch ----------------

extern "C" void kernel_launch(void* const* d_in, const int* in_sizes, int n_in,
                              void* d_out, int out_size, void* d_ws, size_t ws_size,
                              hipStream_t stream) {
    const float* inp = (const float*)d_in[0];
    const float* hid = (const float*)d_in[1];
    const int*   ei  = (const int*)d_in[2];
    const float* ew  = (const float*)d_in[3];
    const float* W   = (const float*)d_in[4];
    const float* bv  = (const float*)d_in[5];
    float* out = (float*)d_out;

    char* base = (char*)d_ws;
    size_t off = 0;
    auto carve = [&](size_t bytes) -> char* {
        char* q = base + off;
        off += (bytes + 255) & ~(size_t)255;
        return q;
    };
    int*   cnt  = (int*)carve((size_t)2 * NN * 4);
    int*   fcnt = (int*)carve((size_t)2 * NN * 4);
    int*   rp   = (int*)carve((size_t)2 * (NN + 1) * 4);
    int*   esrc = (int*)carve((size_t)2 * NE * 4);
    float* ewt  = (float*)carve((size_t)2 * NE * 4);
    float* comb = (float*)carve((size_t)NN * FC * 4);
    float* ytmp = (float*)carve((size_t)NN * FH * 4);
    float* Bb0  = (float*)carve((size_t)NN * FH * 4);
    float* Bb1  = (float*)carve((size_t)NN * FH * 4);
    float* Bb2  = (float*)carve((size_t)NN * FH * 4);
    float* Sacc = (float*)carve((size_t)NN * FH * 4);
    float* rbuf = (float*)carve((size_t)NN * FH * 4);

    hipMemsetAsync(cnt, 0, (size_t)2 * NN * 4, stream);
    hipMemsetAsync(fcnt, 0, (size_t)2 * NN * 4, stream);
    k_hist<<<5000, 256, 0, stream>>>(ei, cnt);
    k_scan<<<2, 1024, 0, stream>>>(cnt, rp);
    k_fill<<<5000, 256, 0, stream>>>(ei, ew, rp, fcnt, esrc, ewt);
    k_comb<<<5000, 256, 0, stream>>>(inp, hid, comb);

    float* B[3] = {Bb0, Bb1, Bb2};
    auto gconv = [&](float* dst) {
        // block 0: identity term x @ W_0 -> dst
        k_gemm<<<625, 256, 0, stream>>>(comb, W, dst, 0);
        for (int k = 0; k < NK; ++k) {
            const int* rpk = rp + k * (NN + 1);
            const int* esk = esrc + (size_t)k * NE;
            const float* ewk = ewt + (size_t)k * NE;
            // Clenshaw: b_10 = y_10
            k_gemm<<<625, 256, 0, stream>>>(comb, W, B[0], 10 * k + 10);
            // b_9 = y_9 + 2 A b_10
            k_gemm<<<625, 256, 0, stream>>>(comb, W, ytmp, 10 * k + 9);
            k_spmm<<<5000, 256, 0, stream>>>(rpk, esk, ewk, B[0], (const float*)nullptr, ytmp, B[1], 0);
            int cur = 1, prev = 0;
            for (int j = 8; j >= 1; --j) {
                int nxt = 3 - cur - prev;
                k_gemm<<<625, 256, 0, stream>>>(comb, W, ytmp, 10 * k + j);
                k_spmm<<<5000, 256, 0, stream>>>(rpk, esk, ewk, B[cur], B[prev], ytmp, B[nxt], 1);
                prev = cur; cur = nxt;
            }
            // S += A b_1 - b_2
            k_spmm<<<5000, 256, 0, stream>>>(rpk, esk, ewk, B[cur], B[prev], (const float*)nullptr, dst, 2);
        }
    };

    // gconv #1 on [input, hidden]  -> r (== u, the reference computes it twice identically)
    gconv(Sacc);
    k_act<<<10000, 256, 0, stream>>>(Sacc, bv, hid, rbuf, comb);   // r = sigmoid(.), comb := [input, r*hidden]
    // gconv #2 on [input, r*hidden] -> C (pre-activation)
    gconv(Sacc);
    // out = u*hidden + (1-u)*sigmoid(C_pre)
    k_final<<<10000, 256, 0, stream>>>(Sacc, bv, hid, rbuf, out);
}

// Round 3
// 2628.402 us; speedup vs baseline: 1.5650x; 1.5650x over previous
//
#include <hip/hip_runtime.h>

#define NN 20000
#define NK 2
#define FC 256    // combined width
#define FH 128    // hidden width
#define NE 640000
#define NB 21     // weight blocks

typedef short v8s __attribute__((ext_vector_type(8)));
typedef float v4f __attribute__((ext_vector_type(4)));

__device__ __forceinline__ float bf2f(unsigned short h) {
    union { unsigned int u; float f; } v; v.u = ((unsigned int)h) << 16; return v.f;
}
__device__ __forceinline__ unsigned short f2bf(float f) {
    union { float f; unsigned int u; } v; v.f = f;
    unsigned int r = v.u + 0x7FFF + ((v.u >> 16) & 1);   // RNE
    return (unsigned short)(r >> 16);
}

// ---------------- CSR build ----------------

__global__ __launch_bounds__(256) void k_hist(const int* __restrict__ ei, int* __restrict__ cnt) {
    int i = blockIdx.x * 256 + threadIdx.x;          // 0 .. 2*NE-1
    int k = i / NE, e = i - k * NE;
    int dst = ei[(size_t)k * 2 * NE + NE + e];
    atomicAdd(&cnt[k * NN + dst], 1);
}

__global__ __launch_bounds__(1024) void k_scan(const int* __restrict__ cnt, int* __restrict__ rp) {
    int k = blockIdx.x;
    __shared__ int part[1024];
    int t = threadIdx.x;
    int loc[20];
    int s = 0;
    if (t < 1000) {
#pragma unroll
        for (int j = 0; j < 20; ++j) { loc[j] = cnt[k * NN + t * 20 + j]; s += loc[j]; }
    }
    part[t] = s;
    __syncthreads();
    for (int off = 1; off < 1024; off <<= 1) {
        int add = (t >= off) ? part[t - off] : 0;
        __syncthreads();
        part[t] += add;
        __syncthreads();
    }
    int excl = (t == 0) ? 0 : part[t - 1];
    if (t < 1000) {
        int run = excl;
#pragma unroll
        for (int j = 0; j < 20; ++j) { rp[k * (NN + 1) + t * 20 + j] = run; run += loc[j]; }
        if (t == 999) rp[k * (NN + 1) + NN] = run;
    }
}

__global__ __launch_bounds__(256) void k_fill(const int* __restrict__ ei, const float* __restrict__ ew,
                                              const int* __restrict__ rp, int* __restrict__ fcnt,
                                              int2* __restrict__ ep) {
    int i = blockIdx.x * 256 + threadIdx.x;
    int k = i / NE, e = i - k * NE;
    int src = ei[(size_t)k * 2 * NE + e];
    int dst = ei[(size_t)k * 2 * NE + NE + e];
    int pos = rp[k * (NN + 1) + dst] + atomicAdd(&fcnt[k * NN + dst], 1);
    int2 pk; pk.x = src; pk.y = __float_as_int(ew[(size_t)k * NE + e]);
    ep[(size_t)k * NE + pos] = pk;
}

// ---------------- combined build (bf16) ----------------

__global__ __launch_bounds__(256) void k_comb(const float* __restrict__ in, const float* __restrict__ hid,
                                              unsigned short* __restrict__ comb) {
    int i = blockIdx.x * 256 + threadIdx.x;          // 0 .. NN*64-1
    int r = i >> 6, c4 = i & 63;
    float4 v = (c4 < 32) ? ((const float4*)(in  + (size_t)r * FH))[c4]
                         : ((const float4*)(hid + (size_t)r * FH))[c4 - 32];
    ushort4 o; o.x = f2bf(v.x); o.y = f2bf(v.y); o.z = f2bf(v.z); o.w = f2bf(v.w);
    *(ushort4*)&comb[(size_t)r * FC + c4 * 4] = o;
}

// ---------------- W convert + transpose: Wt[blk][n][k] bf16 ----------------

__global__ __launch_bounds__(256) void k_wcvt(const float* __restrict__ W, unsigned short* __restrict__ Wt) {
    int i = blockIdx.x * 256 + threadIdx.x;          // NB*FH*FC = 688128
    int blk = i >> 15;
    int rem = i & 32767;
    int n = rem >> 8, kk = rem & 255;
    Wt[i] = f2bf(W[((size_t)blk * FC + kk) * FH + n]);
}

// ---------------- MFMA GEMM: y = comb(bf16) @ W_blk, blk = jstep + 10*blockIdx.y ----------------
// BM=64, BN=128, K=256 in 4 chunks of 64. 4 waves; wave w owns cols [w*32, w*32+32).

#define LDK 72

__global__ __launch_bounds__(256, 2) void k_gemm(const unsigned short* __restrict__ X,
        const unsigned short* __restrict__ Wt, unsigned short* __restrict__ outb,
        float* __restrict__ outf, int jstep) {
    __shared__ unsigned short Xs[64 * LDK];
    __shared__ unsigned short Ws[128 * LDK];
    int t = threadIdx.x;
    int w = t >> 6, l = t & 63;
    int l15 = l & 15, lg = l >> 4;
    int bm = blockIdx.x * 64;
    int blk = jstep + 10 * blockIdx.y;
    const unsigned short* Wb = Wt + (size_t)blk * FH * FC;
    v4f acc[4][2];
#pragma unroll
    for (int a = 0; a < 4; ++a)
#pragma unroll
        for (int b = 0; b < 2; ++b) acc[a][b] = (v4f){0.f, 0.f, 0.f, 0.f};

    for (int c = 0; c < 4; ++c) {
#pragma unroll
        for (int i = 0; i < 2; ++i) {                 // X tile: 64x64 bf16
            int s = t + i * 256;
            int row = s >> 3, c8 = s & 7;
            int grow = bm + row; if (grow >= NN) grow = NN - 1;
            *(v8s*)&Xs[row * LDK + c8 * 8] = *(const v8s*)(X + (size_t)grow * FC + c * 64 + c8 * 8);
        }
#pragma unroll
        for (int i = 0; i < 4; ++i) {                 // W tile: 128 n x 64 k
            int s = t + i * 256;
            int n = s >> 3, k8 = s & 7;
            *(v8s*)&Ws[n * LDK + k8 * 8] = *(const v8s*)(Wb + (size_t)n * FC + c * 64 + k8 * 8);
        }
        __syncthreads();
#pragma unroll
        for (int ks2 = 0; ks2 < 2; ++ks2) {
            int ko = ks2 * 32 + lg * 8;
            v8s a[4], b[2];
#pragma unroll
            for (int mf = 0; mf < 4; ++mf) a[mf] = *(const v8s*)&Xs[(mf * 16 + l15) * LDK + ko];
#pragma unroll
            for (int nf = 0; nf < 2; ++nf) b[nf] = *(const v8s*)&Ws[(w * 32 + nf * 16 + l15) * LDK + ko];
#pragma unroll
            for (int mf = 0; mf < 4; ++mf)
#pragma unroll
                for (int nf = 0; nf < 2; ++nf)
                    acc[mf][nf] = __builtin_amdgcn_mfma_f32_16x16x32_bf16(a[mf], b[nf], acc[mf][nf], 0, 0, 0);
        }
        __syncthreads();
    }
    unsigned short* ob = outb ? outb + (size_t)blockIdx.y * NN * FH : (unsigned short*)0;
#pragma unroll
    for (int mf = 0; mf < 4; ++mf) {
        int grow0 = bm + mf * 16 + lg * 4;           // C/D: col=lane&15, row=(lane>>4)*4+reg  [m89]
#pragma unroll
        for (int nf = 0; nf < 2; ++nf) {
            int gcol = w * 32 + nf * 16 + l15;
#pragma unroll
            for (int r = 0; r < 4; ++r) {
                int grow = grow0 + r;
                if (grow < NN) {
                    if (outf) outf[(size_t)grow * FH + gcol] = acc[mf][nf][r];
                    else      ob[(size_t)grow * FH + gcol] = f2bf(acc[mf][nf][r]);
                }
            }
        }
    }
}

// ---------------- Clenshaw SPMM (both supports in one dispatch; bf16 state) ----------------
// mode 0: out = y + 2*(A b1)
// mode 1: out = y + 2*(A b1) - b2
// mode 2: out = (A b1) - b2

__global__ __launch_bounds__(256) void k_spmm(const int* __restrict__ rp, const int2* __restrict__ ep,
        const unsigned short* __restrict__ b1, const unsigned short* __restrict__ b2,
        const unsigned short* __restrict__ y, unsigned short* __restrict__ outp, int mode) {
    int gid = blockIdx.x * 256 + threadIdx.x;        // 2*NN waves total
    int wid = gid >> 6, lane = gid & 63;
    int k = (wid >= NN) ? 1 : 0;
    int row = wid - k * NN;
    int beg = rp[k * (NN + 1) + row], end = rp[k * (NN + 1) + row + 1];
    const unsigned int* b1u = (const unsigned int*)b1 + (size_t)k * NN * 64;
    const int2* epk = ep + (size_t)k * NE;
    float ax = 0.f, ay = 0.f;
    for (int e = beg; e < end; ++e) {
        int2 pe = epk[e];
        float wgt = __int_as_float(pe.y);
        unsigned int v = b1u[(size_t)pe.x * 64 + lane];
        ax += wgt * bf2f((unsigned short)(v & 0xffffu));
        ay += wgt * bf2f((unsigned short)(v >> 16));
    }
    size_t o = (size_t)(k * NN + row) * 64 + lane;
    float rx, ry;
    if (mode == 0) {
        unsigned int yv = ((const unsigned int*)y)[o];
        rx = bf2f((unsigned short)(yv & 0xffffu)) + 2.f * ax;
        ry = bf2f((unsigned short)(yv >> 16))     + 2.f * ay;
    } else if (mode == 1) {
        unsigned int yv = ((const unsigned int*)y)[o];
        unsigned int bv = ((const unsigned int*)b2)[o];
        rx = bf2f((unsigned short)(yv & 0xffffu)) + 2.f * ax - bf2f((unsigned short)(bv & 0xffffu));
        ry = bf2f((unsigned short)(yv >> 16))     + 2.f * ay - bf2f((unsigned short)(bv >> 16));
    } else {
        unsigned int bv = ((const unsigned int*)b2)[o];
        rx = ax - bf2f((unsigned short)(bv & 0xffffu));
        ry = ay - bf2f((unsigned short)(bv >> 16));
    }
    ((unsigned int*)outp)[o] = (unsigned int)f2bf(rx) | ((unsigned int)f2bf(ry) << 16);
}

// ---------------- activations ----------------

__global__ __launch_bounds__(256) void k_act(const float* __restrict__ S0, const unsigned short* __restrict__ Sk,
        const float* __restrict__ bvec, const float* __restrict__ hid,
        float* __restrict__ rbuf, unsigned short* __restrict__ comb) {
    int i = blockIdx.x * 256 + threadIdx.x;          // NN*128
    int r = i >> 7, c = i & 127;
    float s = S0[i] + bf2f(Sk[i]) + bf2f(Sk[(size_t)NN * FH + i]) + bvec[c];
    float u = 1.f / (1.f + __expf(-s));
    rbuf[i] = u;
    comb[(size_t)r * FC + FH + c] = f2bf(u * hid[i]);
}

__global__ __launch_bounds__(256) void k_final(const float* __restrict__ S0, const unsigned short* __restrict__ Sk,
        const float* __restrict__ bvec, const float* __restrict__ hid,
        const float* __restrict__ rbuf, float* __restrict__ out) {
    int i = blockIdx.x * 256 + threadIdx.x;
    int c = i & 127;
    float s = S0[i] + bf2f(Sk[i]) + bf2f(Sk[(size_t)NN * FH + i]) + bvec[c];
    float C = 1.f / (1.f + __expf(-s));
    float u = rbuf[i];
    out[i] = u * hid[i] + (1.f - u) * C;
}

// ---------------- launch ----------------

extern "C" void kernel_launch(void* const* d_in, const int* in_sizes, int n_in,
                              void* d_out, int out_size, void* d_ws, size_t ws_size,
                              hipStream_t stream) {
    const float* inp = (const float*)d_in[0];
    const float* hid = (const float*)d_in[1];
    const int*   ei  = (const int*)d_in[2];
    const float* ew  = (const float*)d_in[3];
    const float* W   = (const float*)d_in[4];
    const float* bv  = (const float*)d_in[5];
    float* out = (float*)d_out;

    char* base = (char*)d_ws;
    size_t off = 0;
    auto carve = [&](size_t bytes) -> char* {
        char* q = base + off;
        off += (bytes + 255) & ~(size_t)255;
        return q;
    };
    int*            cnt  = (int*)carve((size_t)2 * NN * 4);
    int*            fcnt = (int*)carve((size_t)2 * NN * 4);
    int*            rp   = (int*)carve((size_t)2 * (NN + 1) * 4);
    int2*           ep   = (int2*)carve((size_t)2 * NE * 8);
    unsigned short* comb = (unsigned short*)carve((size_t)NN * FC * 2);
    unsigned short* Wt   = (unsigned short*)carve((size_t)NB * FH * FC * 2);
    unsigned short* ytmp = (unsigned short*)carve((size_t)2 * NN * FH * 2);
    unsigned short* Bs0  = (unsigned short*)carve((size_t)2 * NN * FH * 2);
    unsigned short* Bs1  = (unsigned short*)carve((size_t)2 * NN * FH * 2);
    unsigned short* Bs2  = (unsigned short*)carve((size_t)2 * NN * FH * 2);
    float*          Sacc = (float*)carve((size_t)NN * FH * 4);
    float*          rbuf = (float*)carve((size_t)NN * FH * 4);
    unsigned short* Bsl[3] = {Bs0, Bs1, Bs2};

    hipMemsetAsync(cnt, 0, (size_t)2 * NN * 4, stream);
    hipMemsetAsync(fcnt, 0, (size_t)2 * NN * 4, stream);
    k_hist<<<5000, 256, 0, stream>>>(ei, cnt);
    k_scan<<<2, 1024, 0, stream>>>(cnt, rp);
    k_fill<<<5000, 256, 0, stream>>>(ei, ew, rp, fcnt, ep);
    k_comb<<<5000, 256, 0, stream>>>(inp, hid, comb);
    k_wcvt<<<2688, 256, 0, stream>>>(W, Wt);

    auto gemm = [&](int j, unsigned short* ob, float* of, int gy) {
        k_gemm<<<dim3(313, gy), 256, 0, stream>>>(comb, Wt, ob, of, j);
    };
    auto spmm = [&](unsigned short* b1, unsigned short* b2, unsigned short* y,
                    unsigned short* o, int mode) {
        k_spmm<<<10000, 256, 0, stream>>>(rp, ep, b1, b2, y, o, mode);
    };

    // one gconv: returns the bf16 buffer holding per-support S_k = A b1 - b2 (both supports)
    auto gconv = [&]() -> unsigned short* {
        gemm(0, nullptr, Sacc, 1);                   // identity block -> fp32 Sacc
        gemm(10, Bsl[0], nullptr, 2);                // b10 = y10 (both supports)
        gemm(9, ytmp, nullptr, 2);
        spmm(Bsl[0], nullptr, ytmp, Bsl[1], 0);      // b9 = y9 + 2A b10
        int cur = 1, prev = 0;
        for (int j = 8; j >= 1; --j) {
            int nxt = 3 - cur - prev;
            gemm(j, ytmp, nullptr, 2);
            spmm(Bsl[cur], Bsl[prev], ytmp, Bsl[nxt], 1);
            prev = cur; cur = nxt;
        }
        int fr = 3 - cur - prev;
        spmm(Bsl[cur], Bsl[prev], nullptr, Bsl[fr], 2);  // S_k = A b1 - b2
        return Bsl[fr];
    };

    // gconv #1 on [input, hidden] -> u (== r; reference computes it twice identically)
    unsigned short* S1 = gconv();
    k_act<<<10000, 256, 0, stream>>>(Sacc, S1, bv, hid, rbuf, comb);  // comb := [input, r*hidden]
    // gconv #2 on [input, r*hidden] -> C pre-activation
    unsigned short* S2 = gconv();
    k_final<<<10000, 256, 0, stream>>>(Sacc, S2, bv, hid, rbuf, out);
}

// Round 4
// 1088.225 us; speedup vs baseline: 3.7799x; 2.4153x over previous
//
#include <hip/hip_runtime.h>

#define NN 20000
#define NK 2
#define FC 256    // combined width
#define FH 128    // hidden width
#define NE 640000
#define NB 21     // weight blocks

typedef short v8s __attribute__((ext_vector_type(8)));
typedef float v4f __attribute__((ext_vector_type(4)));

__device__ __forceinline__ float bf2f(unsigned short h) {
    union { unsigned int u; float f; } v; v.u = ((unsigned int)h) << 16; return v.f;
}
__device__ __forceinline__ unsigned short f2bf(float f) {
    union { float f; unsigned int u; } v; v.f = f;
    unsigned int r = v.u + 0x7FFF + ((v.u >> 16) & 1);   // RNE
    return (unsigned short)(r >> 16);
}
__device__ __forceinline__ float bflo(unsigned int v) {
    union { unsigned int u; float f; } t; t.u = v << 16; return t.f;
}
__device__ __forceinline__ float bfhi(unsigned int v) {
    union { unsigned int u; float f; } t; t.u = v & 0xffff0000u; return t.f;
}

// ---------------- CSR build ----------------

__global__ __launch_bounds__(256) void k_hist(const int* __restrict__ ei, int* __restrict__ cnt) {
    int i = blockIdx.x * 256 + threadIdx.x;          // 0 .. 2*NE-1
    int k = i / NE, e = i - k * NE;
    int dst = ei[(size_t)k * 2 * NE + NE + e];
    atomicAdd(&cnt[k * NN + dst], 1);
}

__global__ __launch_bounds__(1024) void k_scan(const int* __restrict__ cnt, int* __restrict__ rp) {
    int k = blockIdx.x;
    __shared__ int part[1024];
    int t = threadIdx.x;
    int loc[20];
    int s = 0;
    if (t < 1000) {
#pragma unroll
        for (int j = 0; j < 20; ++j) { loc[j] = cnt[k * NN + t * 20 + j]; s += loc[j]; }
    }
    part[t] = s;
    __syncthreads();
    for (int off = 1; off < 1024; off <<= 1) {
        int add = (t >= off) ? part[t - off] : 0;
        __syncthreads();
        part[t] += add;
        __syncthreads();
    }
    int excl = (t == 0) ? 0 : part[t - 1];
    if (t < 1000) {
        int run = excl;
#pragma unroll
        for (int j = 0; j < 20; ++j) { rp[k * (NN + 1) + t * 20 + j] = run; run += loc[j]; }
        if (t == 999) rp[k * (NN + 1) + NN] = run;
    }
}

__global__ __launch_bounds__(256) void k_fill(const int* __restrict__ ei, const float* __restrict__ ew,
                                              const int* __restrict__ rp, int* __restrict__ fcnt,
                                              int2* __restrict__ ep) {
    int i = blockIdx.x * 256 + threadIdx.x;
    int k = i / NE, e = i - k * NE;
    int src = ei[(size_t)k * 2 * NE + e];
    int dst = ei[(size_t)k * 2 * NE + NE + e];
    int pos = rp[k * (NN + 1) + dst] + atomicAdd(&fcnt[k * NN + dst], 1);
    int2 pk; pk.x = src; pk.y = __float_as_int(ew[(size_t)k * NE + e]);
    ep[(size_t)k * NE + pos] = pk;
}

// ---------------- combined build (bf16) ----------------

__global__ __launch_bounds__(256) void k_comb(const float* __restrict__ in, const float* __restrict__ hid,
                                              unsigned short* __restrict__ comb) {
    int i = blockIdx.x * 256 + threadIdx.x;          // 0 .. NN*64-1
    int r = i >> 6, c4 = i & 63;
    float4 v = (c4 < 32) ? ((const float4*)(in  + (size_t)r * FH))[c4]
                         : ((const float4*)(hid + (size_t)r * FH))[c4 - 32];
    ushort4 o; o.x = f2bf(v.x); o.y = f2bf(v.y); o.z = f2bf(v.z); o.w = f2bf(v.w);
    *(ushort4*)&comb[(size_t)r * FC + c4 * 4] = o;
}

// ---------------- W convert + transpose: Wt[blk][n][k] bf16 ----------------

__global__ __launch_bounds__(256) void k_wcvt(const float* __restrict__ W, unsigned short* __restrict__ Wt) {
    int i = blockIdx.x * 256 + threadIdx.x;          // NB*FH*FC = 688128
    int blk = i >> 15;
    int rem = i & 32767;
    int n = rem >> 8, kk = rem & 255;
    Wt[i] = f2bf(W[((size_t)blk * FC + kk) * FH + n]);
}

// ---------------- MFMA GEMM: y = comb(bf16) @ W_blk, blk = jstep + 10*blockIdx.y ----------------

#define LDK 72

__global__ __launch_bounds__(256, 2) void k_gemm(const unsigned short* __restrict__ X,
        const unsigned short* __restrict__ Wt, unsigned short* __restrict__ outb,
        float* __restrict__ outf, int jstep) {
    __shared__ unsigned short Xs[64 * LDK];
    __shared__ unsigned short Ws[128 * LDK];
    int t = threadIdx.x;
    int w = t >> 6, l = t & 63;
    int l15 = l & 15, lg = l >> 4;
    int bm = blockIdx.x * 64;
    int blk = jstep + 10 * blockIdx.y;
    const unsigned short* Wb = Wt + (size_t)blk * FH * FC;
    v4f acc[4][2];
#pragma unroll
    for (int a = 0; a < 4; ++a)
#pragma unroll
        for (int b = 0; b < 2; ++b) acc[a][b] = (v4f){0.f, 0.f, 0.f, 0.f};

    for (int c = 0; c < 4; ++c) {
#pragma unroll
        for (int i = 0; i < 2; ++i) {                 // X tile: 64x64 bf16
            int s = t + i * 256;
            int row = s >> 3, c8 = s & 7;
            int grow = bm + row; if (grow >= NN) grow = NN - 1;
            *(v8s*)&Xs[row * LDK + c8 * 8] = *(const v8s*)(X + (size_t)grow * FC + c * 64 + c8 * 8);
        }
#pragma unroll
        for (int i = 0; i < 4; ++i) {                 // W tile: 128 n x 64 k
            int s = t + i * 256;
            int n = s >> 3, k8 = s & 7;
            *(v8s*)&Ws[n * LDK + k8 * 8] = *(const v8s*)(Wb + (size_t)n * FC + c * 64 + k8 * 8);
        }
        __syncthreads();
#pragma unroll
        for (int ks2 = 0; ks2 < 2; ++ks2) {
            int ko = ks2 * 32 + lg * 8;
            v8s a[4], b[2];
#pragma unroll
            for (int mf = 0; mf < 4; ++mf) a[mf] = *(const v8s*)&Xs[(mf * 16 + l15) * LDK + ko];
#pragma unroll
            for (int nf = 0; nf < 2; ++nf) b[nf] = *(const v8s*)&Ws[(w * 32 + nf * 16 + l15) * LDK + ko];
#pragma unroll
            for (int mf = 0; mf < 4; ++mf)
#pragma unroll
                for (int nf = 0; nf < 2; ++nf)
                    acc[mf][nf] = __builtin_amdgcn_mfma_f32_16x16x32_bf16(a[mf], b[nf], acc[mf][nf], 0, 0, 0);
        }
        __syncthreads();
    }
    unsigned short* ob = outb ? outb + (size_t)blockIdx.y * NN * FH : (unsigned short*)0;
#pragma unroll
    for (int mf = 0; mf < 4; ++mf) {
        int grow0 = bm + mf * 16 + lg * 4;           // C/D: col=lane&15, row=(lane>>4)*4+reg  [m89]
#pragma unroll
        for (int nf = 0; nf < 2; ++nf) {
            int gcol = w * 32 + nf * 16 + l15;
#pragma unroll
            for (int r = 0; r < 4; ++r) {
                int grow = grow0 + r;
                if (grow < NN) {
                    if (outf) outf[(size_t)grow * FH + gcol] = acc[mf][nf][r];
                    else      ob[(size_t)grow * FH + gcol] = f2bf(acc[mf][nf][r]);
                }
            }
        }
    }
}

// ---------------- Clenshaw SPMM ----------------
// Blocks are remapped so XCDs 0-3 (blockIdx%8 in 0..3) handle support 0 and
// XCDs 4-7 handle support 1 -> per-XCD gather working set 5.12 MB not 10.24 MB.
// Edge metadata: one coalesced int2 load per 64 edges, then readlane -> SGPR
// src/weight; gathers are independent, unrolled 8-deep.
// mode 0: out = y + 2*(A b1)
// mode 1: out = y + 2*(A b1) - b2
// mode 2: out = (A b1) - b2

__global__ __launch_bounds__(256) void k_spmm(const int* __restrict__ rp, const int2* __restrict__ ep,
        const unsigned short* __restrict__ b1, const unsigned short* __restrict__ b2,
        const unsigned short* __restrict__ y, unsigned short* __restrict__ outp, int mode) {
    int wg = blockIdx.x;                 // 10000 = 8 XCDs x 1250 slots
    int xcd = wg & 7, slot = wg >> 3;
    int k = (xcd >= 4) ? 1 : 0;
    int unit = (xcd & 3) * 1250 + slot;  // 0..4999 within support
    int lane = threadIdx.x & 63;
    int row = unit * 4 + (threadIdx.x >> 6);
    int beg = rp[k * (NN + 1) + row], end = rp[k * (NN + 1) + row + 1];
    const unsigned int* b1u = (const unsigned int*)b1 + (size_t)k * NN * 64;
    const long long* epk = (const long long*)(ep + (size_t)k * NE);

    float ax0 = 0.f, ax1 = 0.f, ax2 = 0.f, ax3 = 0.f;
    float ay0 = 0.f, ay1 = 0.f, ay2 = 0.f, ay3 = 0.f;

    for (int e0 = beg; e0 < end; e0 += 64) {
        int idx = e0 + lane;
        long long mye = (idx < end) ? __builtin_nontemporal_load(epk + idx) : 0ll;
        int mx = (int)mye;                       // src
        int my = (int)(mye >> 32);               // weight bits
        int cnt = min(64, end - e0);
        int j = 0;
        for (; j + 8 <= cnt; j += 8) {
            int   s0 = __builtin_amdgcn_readlane(mx, j + 0);
            int   s1 = __builtin_amdgcn_readlane(mx, j + 1);
            int   s2 = __builtin_amdgcn_readlane(mx, j + 2);
            int   s3 = __builtin_amdgcn_readlane(mx, j + 3);
            int   s4 = __builtin_amdgcn_readlane(mx, j + 4);
            int   s5 = __builtin_amdgcn_readlane(mx, j + 5);
            int   s6 = __builtin_amdgcn_readlane(mx, j + 6);
            int   s7 = __builtin_amdgcn_readlane(mx, j + 7);
            unsigned int v0 = b1u[(size_t)s0 * 64 + lane];
            unsigned int v1 = b1u[(size_t)s1 * 64 + lane];
            unsigned int v2 = b1u[(size_t)s2 * 64 + lane];
            unsigned int v3 = b1u[(size_t)s3 * 64 + lane];
            unsigned int v4 = b1u[(size_t)s4 * 64 + lane];
            unsigned int v5 = b1u[(size_t)s5 * 64 + lane];
            unsigned int v6 = b1u[(size_t)s6 * 64 + lane];
            unsigned int v7 = b1u[(size_t)s7 * 64 + lane];
            float w0 = __int_as_float(__builtin_amdgcn_readlane(my, j + 0));
            float w1 = __int_as_float(__builtin_amdgcn_readlane(my, j + 1));
            float w2 = __int_as_float(__builtin_amdgcn_readlane(my, j + 2));
            float w3 = __int_as_float(__builtin_amdgcn_readlane(my, j + 3));
            float w4 = __int_as_float(__builtin_amdgcn_readlane(my, j + 4));
            float w5 = __int_as_float(__builtin_amdgcn_readlane(my, j + 5));
            float w6 = __int_as_float(__builtin_amdgcn_readlane(my, j + 6));
            float w7 = __int_as_float(__builtin_amdgcn_readlane(my, j + 7));
            ax0 += w0 * bflo(v0); ay0 += w0 * bfhi(v0);
            ax1 += w1 * bflo(v1); ay1 += w1 * bfhi(v1);
            ax2 += w2 * bflo(v2); ay2 += w2 * bfhi(v2);
            ax3 += w3 * bflo(v3); ay3 += w3 * bfhi(v3);
            ax0 += w4 * bflo(v4); ay0 += w4 * bfhi(v4);
            ax1 += w5 * bflo(v5); ay1 += w5 * bfhi(v5);
            ax2 += w6 * bflo(v6); ay2 += w6 * bfhi(v6);
            ax3 += w7 * bflo(v7); ay3 += w7 * bfhi(v7);
        }
        for (; j < cnt; ++j) {
            int   s = __builtin_amdgcn_readlane(mx, j);
            float w = __int_as_float(__builtin_amdgcn_readlane(my, j));
            unsigned int v = b1u[(size_t)s * 64 + lane];
            ax0 += w * bflo(v); ay0 += w * bfhi(v);
        }
    }
    float ax = (ax0 + ax1) + (ax2 + ax3);
    float ay = (ay0 + ay1) + (ay2 + ay3);

    size_t o = (size_t)(k * NN + row) * 64 + lane;
    float rx, ry;
    if (mode == 0) {
        unsigned int yv = __builtin_nontemporal_load((const unsigned int*)y + o);
        rx = bflo(yv) + 2.f * ax;
        ry = bfhi(yv) + 2.f * ay;
    } else if (mode == 1) {
        unsigned int yv = __builtin_nontemporal_load((const unsigned int*)y + o);
        unsigned int bv = __builtin_nontemporal_load((const unsigned int*)b2 + o);
        rx = bflo(yv) + 2.f * ax - bflo(bv);
        ry = bfhi(yv) + 2.f * ay - bfhi(bv);
    } else {
        unsigned int bv = __builtin_nontemporal_load((const unsigned int*)b2 + o);
        rx = ax - bflo(bv);
        ry = ay - bfhi(bv);
    }
    unsigned int res = (unsigned int)f2bf(rx) | ((unsigned int)f2bf(ry) << 16);
    __builtin_nontemporal_store(res, (unsigned int*)outp + o);
}

// ---------------- activations ----------------

__global__ __launch_bounds__(256) void k_act(const float* __restrict__ S0, const unsigned short* __restrict__ Sk,
        const float* __restrict__ bvec, const float* __restrict__ hid,
        float* __restrict__ rbuf, unsigned short* __restrict__ comb) {
    int i = blockIdx.x * 256 + threadIdx.x;          // NN*128
    int r = i >> 7, c = i & 127;
    float s = S0[i] + bf2f(Sk[i]) + bf2f(Sk[(size_t)NN * FH + i]) + bvec[c];
    float u = 1.f / (1.f + __expf(-s));
    rbuf[i] = u;
    comb[(size_t)r * FC + FH + c] = f2bf(u * hid[i]);
}

__global__ __launch_bounds__(256) void k_final(const float* __restrict__ S0, const unsigned short* __restrict__ Sk,
        const float* __restrict__ bvec, const float* __restrict__ hid,
        const float* __restrict__ rbuf, float* __restrict__ out) {
    int i = blockIdx.x * 256 + threadIdx.x;
    int c = i & 127;
    float s = S0[i] + bf2f(Sk[i]) + bf2f(Sk[(size_t)NN * FH + i]) + bvec[c];
    float C = 1.f / (1.f + __expf(-s));
    float u = rbuf[i];
    out[i] = u * hid[i] + (1.f - u) * C;
}

// ---------------- launch ----------------

extern "C" void kernel_launch(void* const* d_in, const int* in_sizes, int n_in,
                              void* d_out, int out_size, void* d_ws, size_t ws_size,
                              hipStream_t stream) {
    const float* inp = (const float*)d_in[0];
    const float* hid = (const float*)d_in[1];
    const int*   ei  = (const int*)d_in[2];
    const float* ew  = (const float*)d_in[3];
    const float* W   = (const float*)d_in[4];
    const float* bv  = (const float*)d_in[5];
    float* out = (float*)d_out;

    char* base = (char*)d_ws;
    size_t off = 0;
    auto carve = [&](size_t bytes) -> char* {
        char* q = base + off;
        off += (bytes + 255) & ~(size_t)255;
        return q;
    };
    int*            cnt  = (int*)carve((size_t)2 * NN * 4);
    int*            fcnt = (int*)carve((size_t)2 * NN * 4);
    int*            rp   = (int*)carve((size_t)2 * (NN + 1) * 4);
    int2*           ep   = (int2*)carve((size_t)2 * NE * 8);
    unsigned short* comb = (unsigned short*)carve((size_t)NN * FC * 2);
    unsigned short* Wt   = (unsigned short*)carve((size_t)NB * FH * FC * 2);
    unsigned short* ytmp = (unsigned short*)carve((size_t)2 * NN * FH * 2);
    unsigned short* Bs0  = (unsigned short*)carve((size_t)2 * NN * FH * 2);
    unsigned short* Bs1  = (unsigned short*)carve((size_t)2 * NN * FH * 2);
    unsigned short* Bs2  = (unsigned short*)carve((size_t)2 * NN * FH * 2);
    float*          Sacc = (float*)carve((size_t)NN * FH * 4);
    float*          rbuf = (float*)carve((size_t)NN * FH * 4);
    unsigned short* Bsl[3] = {Bs0, Bs1, Bs2};

    hipMemsetAsync(cnt, 0, (size_t)2 * NN * 4, stream);
    hipMemsetAsync(fcnt, 0, (size_t)2 * NN * 4, stream);
    k_hist<<<5000, 256, 0, stream>>>(ei, cnt);
    k_scan<<<2, 1024, 0, stream>>>(cnt, rp);
    k_fill<<<5000, 256, 0, stream>>>(ei, ew, rp, fcnt, ep);
    k_comb<<<5000, 256, 0, stream>>>(inp, hid, comb);
    k_wcvt<<<2688, 256, 0, stream>>>(W, Wt);

    auto gemm = [&](int j, unsigned short* ob, float* of, int gy) {
        k_gemm<<<dim3(313, gy), 256, 0, stream>>>(comb, Wt, ob, of, j);
    };
    auto spmm = [&](unsigned short* b1, unsigned short* b2, unsigned short* y,
                    unsigned short* o, int mode) {
        k_spmm<<<10000, 256, 0, stream>>>(rp, ep, b1, b2, y, o, mode);
    };

    // one gconv: returns the bf16 buffer holding per-support S_k = A b1 - b2 (both supports)
    auto gconv = [&]() -> unsigned short* {
        gemm(0, nullptr, Sacc, 1);                   // identity block -> fp32 Sacc
        gemm(10, Bsl[0], nullptr, 2);                // b10 = y10 (both supports)
        gemm(9, ytmp, nullptr, 2);
        spmm(Bsl[0], nullptr, ytmp, Bsl[1], 0);      // b9 = y9 + 2A b10
        int cur = 1, prev = 0;
        for (int j = 8; j >= 1; --j) {
            int nxt = 3 - cur - prev;
            gemm(j, ytmp, nullptr, 2);
            spmm(Bsl[cur], Bsl[prev], ytmp, Bsl[nxt], 1);
            prev = cur; cur = nxt;
        }
        int fr = 3 - cur - prev;
        spmm(Bsl[cur], Bsl[prev], nullptr, Bsl[fr], 2);  // S_k = A b1 - b2
        return Bsl[fr];
    };

    // gconv #1 on [input, hidden] -> u (== r; reference computes it twice identically)
    unsigned short* S1 = gconv();
    k_act<<<10000, 256, 0, stream>>>(Sacc, S1, bv, hid, rbuf, comb);  // comb := [input, r*hidden]
    // gconv #2 on [input, r*hidden] -> C pre-activation
    unsigned short* S2 = gconv();
    k_final<<<10000, 256, 0, stream>>>(Sacc, S2, bv, hid, rbuf, out);
}